// Round 1
// baseline (2999.139 us; speedup 1.0000x reference)
//
#include <hip/hip_runtime.h>
#include <hip/hip_bf16.h>

#define NB 4
#define NS 2048
#define ND 1024
#define NH 16
#define NHD 64
#define NM (NB * NS)   // 8192 rows

// ---------------------------------------------------------------------------
// Tiled fp32 GEMM: C = A @ W + bias
//   A: [NM, ND].  ALAY=0: row-major.  ALAY=1: gather from [B,H,S,HD] buffer.
//   W: [ND, ND] row-major (used as x @ W, matching reference).
//   C: OLAY=0: row-major [NM, ND] (d_out).  OLAY=1: scatter to [B,H,S,HD].
// 128x128 tile, BK=8, 256 threads, 8x8 micro-tile per thread.
// ---------------------------------------------------------------------------
template <int ALAY, int OLAY>
__global__ __launch_bounds__(256) void gemm_f32(
    const float* __restrict__ A, const float* __restrict__ W,
    const float* __restrict__ bias, float* __restrict__ C) {
  __shared__ float As[8][128];  // k-major (transposed A tile)
  __shared__ float Bs[8][128];

  const int t  = threadIdx.x;
  const int tx = t & 15;   // -> n
  const int ty = t >> 4;   // -> m
  const int m0 = blockIdx.x * 128;
  const int n0 = blockIdx.y * 128;

  // staging indices
  const int ar = t >> 1;         // A row within tile (0..127)
  const int ac = (t & 1) * 4;    // A k-col (0 or 4)
  const int kb = t >> 5;         // B k-row (0..7)
  const int nb = (t & 31) * 4;   // B n-col

  float acc[8][8];
#pragma unroll
  for (int i = 0; i < 8; ++i)
#pragma unroll
    for (int j = 0; j < 8; ++j) acc[i][j] = 0.f;

  for (int k0 = 0; k0 < ND; k0 += 8) {
    float4 av, bv;
    if (ALAY == 0) {
      av = *(const float4*)(A + (size_t)(m0 + ar) * ND + (k0 + ac));
    } else {
      const int m  = m0 + ar;
      const int bb = m >> 11, ss = m & (NS - 1);
      const int k  = k0 + ac;
      const int hh = k >> 6, hd = k & (NHD - 1);
      av = *(const float4*)(A + (((size_t)bb * NH + hh) * NS + ss) * NHD + hd);
    }
    bv = *(const float4*)(W + (size_t)(k0 + kb) * ND + (n0 + nb));

    __syncthreads();  // previous iteration's LDS reads done before overwrite
    As[ac + 0][ar] = av.x;
    As[ac + 1][ar] = av.y;
    As[ac + 2][ar] = av.z;
    As[ac + 3][ar] = av.w;
    *(float4*)&Bs[kb][nb] = bv;
    __syncthreads();

#pragma unroll
    for (int kk = 0; kk < 8; ++kk) {
      float a[8], b[8];
      *(float4*)&a[0] = *(const float4*)&As[kk][ty * 8];
      *(float4*)&a[4] = *(const float4*)&As[kk][ty * 8 + 4];
      *(float4*)&b[0] = *(const float4*)&Bs[kk][tx * 8];
      *(float4*)&b[4] = *(const float4*)&Bs[kk][tx * 8 + 4];
#pragma unroll
      for (int i = 0; i < 8; ++i)
#pragma unroll
        for (int j = 0; j < 8; ++j) acc[i][j] = fmaf(a[i], b[j], acc[i][j]);
    }
  }

#pragma unroll
  for (int i = 0; i < 8; ++i) {
    const int m = m0 + ty * 8 + i;
#pragma unroll
    for (int jj = 0; jj < 2; ++jj) {
      const int n = n0 + tx * 8 + jj * 4;
      float4 o;
      o.x = acc[i][jj * 4 + 0] + bias[n + 0];
      o.y = acc[i][jj * 4 + 1] + bias[n + 1];
      o.z = acc[i][jj * 4 + 2] + bias[n + 2];
      o.w = acc[i][jj * 4 + 3] + bias[n + 3];
      if (OLAY == 0) {
        *(float4*)(C + (size_t)m * ND + n) = o;
      } else {
        const int bb = m >> 11, ss = m & (NS - 1);
        const int hh = n >> 6, hd = n & (NHD - 1);
        *(float4*)(C + (((size_t)bb * NH + hh) * NS + ss) * NHD + hd) = o;
      }
    }
  }
}

// ---------------------------------------------------------------------------
// Flash attention, fp32. One q-row per thread, 256 rows per block.
// K/V staged in LDS in 32-row tiles; LDS reads are wave-broadcast.
// Online softmax (running max / running sum) in registers.
// O written in-place over the Q buffer (each row read-once-then-written by
// its owning thread only).
// ---------------------------------------------------------------------------
__global__ __launch_bounds__(256) void attn_f32(
    const float* __restrict__ Q, const float* __restrict__ K,
    const float* __restrict__ V, float* __restrict__ O) {
  __shared__ float Kt[32][64];
  __shared__ float Vt[32][64];

  const int t   = threadIdx.x;
  const int bh  = blockIdx.y;
  const int row = blockIdx.x * 256 + t;
  const float scale = 0.125f;  // 1/sqrt(64)

  const float* qp = Q + ((size_t)bh * NS + row) * NHD;
  float q[64], o[64];
#pragma unroll
  for (int d = 0; d < 64; d += 4) {
    float4 v4 = *(const float4*)(qp + d);
    q[d + 0] = v4.x * scale;
    q[d + 1] = v4.y * scale;
    q[d + 2] = v4.z * scale;
    q[d + 3] = v4.w * scale;
  }
#pragma unroll
  for (int d = 0; d < 64; ++d) o[d] = 0.f;

  float mrun = -1e30f, lrun = 0.f;
  const float* kbase = K + (size_t)bh * NS * NHD;
  const float* vbase = V + (size_t)bh * NS * NHD;

  for (int kt = 0; kt < NS / 32; ++kt) {
    __syncthreads();
#pragma unroll
    for (int i = 0; i < 2; ++i) {
      const int idx = i * 1024 + t * 4;
      const int rr = idx >> 6, cc = idx & 63;
      *(float4*)&Kt[rr][cc] =
          *(const float4*)(kbase + ((size_t)kt * 32 + rr) * NHD + cc);
      *(float4*)&Vt[rr][cc] =
          *(const float4*)(vbase + ((size_t)kt * 32 + rr) * NHD + cc);
    }
    __syncthreads();

    float s[32];
#pragma unroll
    for (int kk = 0; kk < 32; ++kk) {
      float acc = 0.f;
#pragma unroll
      for (int d = 0; d < 64; d += 4) {
        float4 kv = *(const float4*)&Kt[kk][d];
        acc = fmaf(q[d + 0], kv.x, acc);
        acc = fmaf(q[d + 1], kv.y, acc);
        acc = fmaf(q[d + 2], kv.z, acc);
        acc = fmaf(q[d + 3], kv.w, acc);
      }
      s[kk] = acc;
    }

    float tmax = mrun;
#pragma unroll
    for (int kk = 0; kk < 32; ++kk) tmax = fmaxf(tmax, s[kk]);
    const float alpha = __expf(mrun - tmax);
    mrun = tmax;
    lrun *= alpha;
#pragma unroll
    for (int d = 0; d < 64; ++d) o[d] *= alpha;

#pragma unroll
    for (int kk = 0; kk < 32; ++kk) {
      const float p = __expf(s[kk] - mrun);
      lrun += p;
#pragma unroll
      for (int d = 0; d < 64; d += 4) {
        float4 vv = *(const float4*)&Vt[kk][d];
        o[d + 0] = fmaf(p, vv.x, o[d + 0]);
        o[d + 1] = fmaf(p, vv.y, o[d + 1]);
        o[d + 2] = fmaf(p, vv.z, o[d + 2]);
        o[d + 3] = fmaf(p, vv.w, o[d + 3]);
      }
    }
  }

  const float inv = 1.f / lrun;
  float* op = O + ((size_t)bh * NS + row) * NHD;
#pragma unroll
  for (int d = 0; d < 64; d += 4) {
    float4 v4;
    v4.x = o[d + 0] * inv;
    v4.y = o[d + 1] * inv;
    v4.z = o[d + 2] * inv;
    v4.w = o[d + 3] * inv;
    *(float4*)(op + d) = v4;
  }
}

// ---------------------------------------------------------------------------
extern "C" void kernel_launch(void* const* d_in, const int* in_sizes, int n_in,
                              void* d_out, int out_size, void* d_ws,
                              size_t ws_size, hipStream_t stream) {
  const float* x  = (const float*)d_in[0];
  const float* Wq = (const float*)d_in[1];
  const float* bq = (const float*)d_in[2];
  const float* Wk = (const float*)d_in[3];
  const float* bk = (const float*)d_in[4];
  const float* Wv = (const float*)d_in[5];
  const float* bv = (const float*)d_in[6];
  const float* Wo = (const float*)d_in[7];
  const float* bo = (const float*)d_in[8];
  float* out = (float*)d_out;

  const size_t qkv_elems = (size_t)NB * NH * NS * NHD;  // 8.39M floats each
  float* wsQ = (float*)d_ws;
  float* wsK = wsQ + qkv_elems;
  // V lives in d_out (same element count as one head buffer). Attention
  // finishes reading V before the final GEMM overwrites d_out (stream order).
  float* wsV = out;

  dim3 gemm_grid(NM / 128, ND / 128);  // (64, 8)
  gemm_f32<0, 1><<<gemm_grid, 256, 0, stream>>>(x, Wq, bq, wsQ);
  gemm_f32<0, 1><<<gemm_grid, 256, 0, stream>>>(x, Wk, bk, wsK);
  gemm_f32<0, 1><<<gemm_grid, 256, 0, stream>>>(x, Wv, bv, wsV);

  attn_f32<<<dim3(NS / 256, NB * NH), 256, 0, stream>>>(wsQ, wsK, wsV, wsQ);

  gemm_f32<1, 0><<<gemm_grid, 256, 0, stream>>>(wsQ, Wo, bo, out);
}

// Round 2
// 286.015 us; speedup vs baseline: 10.4860x; 10.4860x over previous
//
#include <hip/hip_runtime.h>
#include <hip/hip_bf16.h>

#define NB 4
#define NS 2048
#define ND 1024
#define NH 16
#define NHD 64
#define NM (NB * NS)  // 8192

typedef __attribute__((ext_vector_type(8))) short bf16x8;
typedef __attribute__((ext_vector_type(4))) float f32x4;

typedef const unsigned int __attribute__((address_space(1)))* gas_t;
typedef unsigned int __attribute__((address_space(3)))* las_t;

__device__ __forceinline__ void gload_lds16(const void* g, void* l) {
  __builtin_amdgcn_global_load_lds((gas_t)g, (las_t)l, 16, 0, 0);
}

__device__ __forceinline__ unsigned short f2bf(float f) {
  union { __hip_bfloat16 h; unsigned short u; } cv;
  cv.h = __float2bfloat16(f);
  return cv.u;
}

// ---------------------------------------------------------------------------
// Transpose + convert: out[n][k] (bf16) = in[k][n] (f32), 1024x1024.
// ---------------------------------------------------------------------------
__global__ __launch_bounds__(256) void transpose_w(
    const float* __restrict__ in, unsigned short* __restrict__ out) {
  __shared__ float tile[64][65];
  const int t = threadIdx.x;
  const int bx = blockIdx.x;  // k tile
  const int by = blockIdx.y;  // n tile
#pragma unroll
  for (int j = 0; j < 4; ++j) {
    const int lin = j * 1024 + t * 4;
    const int r = lin >> 6, c = lin & 63;
    float4 v = *(const float4*)(in + (size_t)(bx * 64 + r) * ND + by * 64 + c);
    tile[r][c + 0] = v.x; tile[r][c + 1] = v.y;
    tile[r][c + 2] = v.z; tile[r][c + 3] = v.w;
  }
  __syncthreads();
#pragma unroll
  for (int j = 0; j < 4; ++j) {
    const int lin = j * 1024 + t * 4;
    const int r = lin >> 6, c = lin & 63;  // r -> out row (n), c -> out col (k)
    ushort4 o;
    o.x = f2bf(tile[c + 0][r]); o.y = f2bf(tile[c + 1][r]);
    o.z = f2bf(tile[c + 2][r]); o.w = f2bf(tile[c + 3][r]);
    *(ushort4*)(out + (size_t)(by * 64 + r) * ND + bx * 64 + c) = o;
  }
}

// ---------------------------------------------------------------------------
// bf16 MFMA GEMM: C = A @ W + bias, M=8192, N=K=1024.
//   ASRC 0: A = fp32 x, reg-staged + converted + swizzled ds_write.
//   ASRC 1: A = bf16 row-major, global_load_lds.
//   B: W^T bf16 [N][K] row-major (global_load_lds, pre-swizzled source).
//   OLAY 0: f32 row-major out.  1: bf16 scatter [B,H,S,HD].  2: bf16 [B,H,HD,S].
// 128x128 tile, BK=32, 4 waves (2x2 of 64x64), 16x16x32 MFMA.
// ---------------------------------------------------------------------------
template <int ASRC, int OLAY>
__global__ __launch_bounds__(256) void gemm_mfma(
    const void* __restrict__ Av, const unsigned short* __restrict__ BT,
    const float* __restrict__ bias, void* __restrict__ Cv) {
  __shared__ unsigned short As[128 * 32];
  __shared__ unsigned short Bs[128 * 32];
  const int t = threadIdx.x;
  const int w = blockIdx.x;
  // XCD swizzle: 8 consecutive-n blocks of one m-panel land on one XCD.
  const int mblk = (w & 7) + ((w >> 6) << 3);  // 0..63
  const int nblk = (w >> 3) & 7;               // 0..7
  const int m0 = mblk * 128, n0 = nblk * 128;
  const int lane = t & 63, wid = t >> 6;
  const int wm = (wid >> 1) * 64, wn = (wid & 1) * 64;
  const int lr = lane & 15, lg = lane >> 4;

  const f32x4 zero4 = {0.f, 0.f, 0.f, 0.f};
  f32x4 acc[4][4];
#pragma unroll
  for (int i = 0; i < 4; ++i)
#pragma unroll
    for (int j = 0; j < 4; ++j) acc[i][j] = zero4;

  const float* Af = (const float*)Av;
  const unsigned short* Ab = (const unsigned short*)Av;

  for (int k0 = 0; k0 < ND; k0 += 32) {
    float4 axv[4];
    if constexpr (ASRC == 0) {
      // issue x loads early (hide under barrier/stage)
#pragma unroll
      for (int j = 0; j < 4; ++j) {
        const int idx = j * 256 + t;  // 4-float chunk
        const int row = idx >> 3, c4 = idx & 7;
        axv[j] = *(const float4*)(Af + (size_t)(m0 + row) * ND + k0 + c4 * 4);
      }
    }
    __syncthreads();  // prev iteration's LDS reads done
#pragma unroll
    for (int j = 0; j < 2; ++j) {
      const int idx = j * 256 + t;  // 16B chunk
      const int row = idx >> 2, cs = idx & 3;
      const int cg = cs ^ ((row >> 1) & 3);  // pre-swizzled global source
      gload_lds16(BT + (size_t)(n0 + row) * ND + k0 + cg * 8, &Bs[idx * 8]);
      if constexpr (ASRC == 1)
        gload_lds16(Ab + (size_t)(m0 + row) * ND + k0 + cg * 8, &As[idx * 8]);
    }
    if constexpr (ASRC == 0) {
#pragma unroll
      for (int j = 0; j < 4; ++j) {
        const int idx = j * 256 + t;
        const int row = idx >> 3, c4 = idx & 7;
        const int cs = c4 >> 1, half = c4 & 1;
        const int slot = cs ^ ((row >> 1) & 3);
        ushort4 o;
        o.x = f2bf(axv[j].x); o.y = f2bf(axv[j].y);
        o.z = f2bf(axv[j].z); o.w = f2bf(axv[j].w);
        *(ushort4*)&As[row * 32 + slot * 8 + half * 4] = o;
      }
    }
    __syncthreads();  // staged data visible (vmcnt+lgkm drained by compiler)

    bf16x8 af[4], bv[4];
#pragma unroll
    for (int mi = 0; mi < 4; ++mi) {
      const int row = wm + mi * 16 + lr;
      const int slot = lg ^ ((row >> 1) & 3);
      af[mi] = *(const bf16x8*)&As[row * 32 + slot * 8];
    }
#pragma unroll
    for (int ni = 0; ni < 4; ++ni) {
      const int row = wn + ni * 16 + lr;
      const int slot = lg ^ ((row >> 1) & 3);
      bv[ni] = *(const bf16x8*)&Bs[row * 32 + slot * 8];
    }
#pragma unroll
    for (int mi = 0; mi < 4; ++mi)
#pragma unroll
      for (int ni = 0; ni < 4; ++ni)
        acc[mi][ni] = __builtin_amdgcn_mfma_f32_16x16x32_bf16(
            af[mi], bv[ni], acc[mi][ni], 0, 0, 0);
  }

  // epilogue: C frag layout col = lane&15 (n), row = lg*4+i (m)
#pragma unroll
  for (int mi = 0; mi < 4; ++mi) {
#pragma unroll
    for (int ni = 0; ni < 4; ++ni) {
      const int mbase = m0 + wm + mi * 16 + lg * 4;
      const int n = n0 + wn + ni * 16 + lr;
      const float bval = bias[n];
      if constexpr (OLAY == 0) {
        float* Cf = (float*)Cv;
#pragma unroll
        for (int i = 0; i < 4; ++i)
          Cf[(size_t)(mbase + i) * ND + n] = acc[mi][ni][i] + bval;
      } else if constexpr (OLAY == 1) {
        unsigned short* Cb = (unsigned short*)Cv;
        const int h = n >> 6, hd = n & 63;
#pragma unroll
        for (int i = 0; i < 4; ++i) {
          const int m = mbase + i;
          const int b = m >> 11, s = m & (NS - 1);
          Cb[(((size_t)b * NH + h) * NS + s) * NHD + hd] =
              f2bf(acc[mi][ni][i] + bval);
        }
      } else {
        unsigned short* Cb = (unsigned short*)Cv;
        const int h = n >> 6, hd = n & 63;
        const int b = mbase >> 11, s = mbase & (NS - 1);
        ushort4 o;
        o.x = f2bf(acc[mi][ni][0] + bval);
        o.y = f2bf(acc[mi][ni][1] + bval);
        o.z = f2bf(acc[mi][ni][2] + bval);
        o.w = f2bf(acc[mi][ni][3] + bval);
        *(ushort4*)&Cb[(((size_t)b * NH + h) * NHD + hd) * NS + s] = o;
      }
    }
  }
}

// ---------------------------------------------------------------------------
// Flash attention, bf16 MFMA. Block = 4 waves x 16 q-rows = 64 q-rows of one
// (b,h). KV tiles of 64 staged in LDS (XOR-swizzled via pre-swizzled source).
// Swapped QK^T: S^T = mfma(K, Q^T) -> q index is lane-local (lane&15).
// P -> per-wave LDS roundtrip to reach B-fragment layout. O^T in MFMA C-regs.
// ---------------------------------------------------------------------------
__global__ __launch_bounds__(256) void attn_mfma(
    const unsigned short* __restrict__ Qb, const unsigned short* __restrict__ Kb,
    const unsigned short* __restrict__ VTb, unsigned short* __restrict__ Aout) {
  __shared__ unsigned short Ks[64 * 64];   // [kv][d], swizzled chunks
  __shared__ unsigned short Vs[64 * 64];   // [d][kv], swizzled chunks
  __shared__ unsigned short Ps[4][16 * 72];  // per-wave P [q][kv], 144B rows
  const int t = threadIdx.x, lane = t & 63, wid = t >> 6;
  const int lr = lane & 15, lg = lane >> 4;
  const int w = blockIdx.x;
  // XCD swizzle: the 32 q-tiles of one (b,h) share one XCD's L2 for K/V.
  const int bh = (w & 7) + ((w >> 8) << 3);  // 0..63
  const int qtile = (w >> 3) & 31;
  const size_t hoff = (size_t)bh * NS * NHD;
  const int q0 = qtile * 64 + wid * 16;

  // hoist Q fragments (B-operand: lane holds Q[q0+lr][kk*32 + lg*8 ..+8])
  bf16x8 qf[2];
#pragma unroll
  for (int kk = 0; kk < 2; ++kk)
    qf[kk] = *(const bf16x8*)(Qb + hoff + (size_t)(q0 + lr) * NHD + kk * 32 + lg * 8);

  const f32x4 zero4 = {0.f, 0.f, 0.f, 0.f};
  f32x4 oacc[4];
#pragma unroll
  for (int i = 0; i < 4; ++i) oacc[i] = zero4;
  float mrun = -3.0e38f, lrun = 0.f;
  const float cexp = 0.18033688f;  // (1/8) * log2(e)

  for (int kv0 = 0; kv0 < NS; kv0 += 64) {
    __syncthreads();
#pragma unroll
    for (int j = 0; j < 2; ++j) {
      const int idx = j * 256 + t;
      const int row = idx >> 3, cs = idx & 7;
      const int cg = cs ^ (row & 7);  // pre-swizzled global source
      gload_lds16(Kb + hoff + (size_t)(kv0 + row) * NHD + cg * 8, &Ks[idx * 8]);
      gload_lds16(VTb + hoff + (size_t)row * NS + kv0 + cg * 8, &Vs[idx * 8]);
    }
    __syncthreads();

    // S^T[kv][q]: A = K rows (kv), B = Q^T
    f32x4 sacc[4];
#pragma unroll
    for (int f = 0; f < 4; ++f) {
      const int row = f * 16 + lr;
      const int sw = row & 7;
      bf16x8 k0v = *(const bf16x8*)&Ks[row * 64 + (lg ^ sw) * 8];
      bf16x8 k1v = *(const bf16x8*)&Ks[row * 64 + ((4 + lg) ^ sw) * 8];
      sacc[f] = __builtin_amdgcn_mfma_f32_16x16x32_bf16(k0v, qf[0], zero4, 0, 0, 0);
      sacc[f] = __builtin_amdgcn_mfma_f32_16x16x32_bf16(k1v, qf[1], sacc[f], 0, 0, 0);
    }

    // online softmax; q fixed per lane (= lr), kv spread over lanes {l,l^16,l^32,l^48}
    float tmax = -3.0e38f;
#pragma unroll
    for (int f = 0; f < 4; ++f)
#pragma unroll
      for (int i = 0; i < 4; ++i) tmax = fmaxf(tmax, sacc[f][i]);
    tmax = fmaxf(tmax, __shfl_xor(tmax, 16));
    tmax = fmaxf(tmax, __shfl_xor(tmax, 32));
    const float mnew = fmaxf(mrun, tmax);
    const float alpha = exp2f(cexp * (mrun - mnew));
    float psum = 0.f;
    float pv[4][4];
#pragma unroll
    for (int f = 0; f < 4; ++f)
#pragma unroll
      for (int i = 0; i < 4; ++i) {
        const float p = exp2f(cexp * (sacc[f][i] - mnew));
        pv[f][i] = p;
        psum += p;
      }
    psum += __shfl_xor(psum, 16);
    psum += __shfl_xor(psum, 32);
    lrun = lrun * alpha + psum;
    mrun = mnew;
#pragma unroll
    for (int i = 0; i < 4; ++i) oacc[i] *= alpha;

    // P -> LDS (per-wave), layout [q][72] so B-frag read is ds_read_b128
    unsigned short* Pw = &Ps[wid][0];
#pragma unroll
    for (int f = 0; f < 4; ++f) {
      ushort4 o;
      o.x = f2bf(pv[f][0]); o.y = f2bf(pv[f][1]);
      o.z = f2bf(pv[f][2]); o.w = f2bf(pv[f][3]);
      *(ushort4*)&Pw[lr * 72 + f * 16 + lg * 4] = o;
    }
    bf16x8 pb0 = *(const bf16x8*)&Pw[lr * 72 + lg * 8];
    bf16x8 pb1 = *(const bf16x8*)&Pw[lr * 72 + 32 + lg * 8];

    // O^T += V^T * P^T
#pragma unroll
    for (int fd = 0; fd < 4; ++fd) {
      const int row = fd * 16 + lr;
      const int sw = row & 7;
      bf16x8 v0 = *(const bf16x8*)&Vs[row * 64 + (lg ^ sw) * 8];
      bf16x8 v1 = *(const bf16x8*)&Vs[row * 64 + ((4 + lg) ^ sw) * 8];
      oacc[fd] = __builtin_amdgcn_mfma_f32_16x16x32_bf16(v0, pb0, oacc[fd], 0, 0, 0);
      oacc[fd] = __builtin_amdgcn_mfma_f32_16x16x32_bf16(v1, pb1, oacc[fd], 0, 0, 0);
    }
  }

  const float inv = 1.0f / lrun;
  const int b = bh >> 4, h = bh & 15;
  const int m = b * NS + q0 + lr;
#pragma unroll
  for (int fd = 0; fd < 4; ++fd) {
    ushort4 o;
    o.x = f2bf(oacc[fd][0] * inv);
    o.y = f2bf(oacc[fd][1] * inv);
    o.z = f2bf(oacc[fd][2] * inv);
    o.w = f2bf(oacc[fd][3] * inv);
    *(ushort4*)&Aout[(size_t)m * ND + h * NHD + fd * 16 + lg * 4] = o;
  }
}

// ---------------------------------------------------------------------------
extern "C" void kernel_launch(void* const* d_in, const int* in_sizes, int n_in,
                              void* d_out, int out_size, void* d_ws,
                              size_t ws_size, hipStream_t stream) {
  const float* x  = (const float*)d_in[0];
  const float* Wq = (const float*)d_in[1];
  const float* bq = (const float*)d_in[2];
  const float* Wk = (const float*)d_in[3];
  const float* bk = (const float*)d_in[4];
  const float* Wv = (const float*)d_in[5];
  const float* bv = (const float*)d_in[6];
  const float* Wo = (const float*)d_in[7];
  const float* bo = (const float*)d_in[8];
  float* out = (float*)d_out;

  // ws layout (67,108,864 B total — round-0-proven size):
  //   [Qb 16.78M][Kb 16.78M][VTb 16.78M][Aattn 16.78M]
  // W^T slots time-share dead regions (stream-serialized):
  //   WTa = Aattn base (dead until attn), WTb = Qb base (dead after attn).
  const size_t BIG = (size_t)NM * ND;  // 8,388,608 bf16 elems
  unsigned short* Qb    = (unsigned short*)d_ws;
  unsigned short* Kb    = Qb + BIG;
  unsigned short* VTb   = Kb + BIG;
  unsigned short* Aattn = VTb + BIG;
  unsigned short* WTa   = Aattn;  // 2MB scratch inside Aattn region
  unsigned short* WTb   = Qb;     // 2MB scratch inside Qb region

  const dim3 tgrid(16, 16);
  transpose_w<<<tgrid, 256, 0, stream>>>(Wq, WTa);
  gemm_mfma<0, 1><<<512, 256, 0, stream>>>(x, WTa, bq, Qb);
  transpose_w<<<tgrid, 256, 0, stream>>>(Wk, WTa);
  gemm_mfma<0, 1><<<512, 256, 0, stream>>>(x, WTa, bk, Kb);
  transpose_w<<<tgrid, 256, 0, stream>>>(Wv, WTa);
  gemm_mfma<0, 2><<<512, 256, 0, stream>>>(x, WTa, bv, VTb);

  attn_mfma<<<2048, 256, 0, stream>>>(Qb, Kb, VTb, Aattn);

  transpose_w<<<tgrid, 256, 0, stream>>>(Wo, WTb);
  gemm_mfma<1, 0><<<512, 256, 0, stream>>>(Aattn, WTb, bo, out);
}